// Round 7
// baseline (6155.212 us; speedup 1.0000x reference)
//
#include <hip/hip_runtime.h>
#include <hip/hip_bf16.h>
#include <stdint.h>

typedef __hip_bfloat16 bf16;
typedef __attribute__((ext_vector_type(8))) short frag16;
typedef __attribute__((ext_vector_type(4))) float f32x4;

#define B_ 2048
#define T_ 64
#define E_ 300
#define H_ 300
#define C_ 1024
#define NE_ 65536
#define V_ 50000
#define HP 320     // padded E/H half of concat-K
#define KC 640     // padded concat K (320 x + 320 h)
#define NP 1280    // padded 4H, gate-interleaved n = 4*j + q

static __device__ __forceinline__ float sigf(float x) {
  x = fminf(fmaxf(x, -30.f), 30.f);
  return 1.f / (1.f + __expf(-x));
}
static __device__ __forceinline__ float tanhfast(float x) {
  x = fminf(fmaxf(x, -15.f), 15.f);
  float e = __expf(2.f * x);
  return (e - 1.f) / (e + 1.f);
}
// read raw float input element i: isb=1 -> bf16, isb=0 -> f32
static __device__ __forceinline__ float ldraw(const void* p, size_t i, int isb) {
  return isb ? __bfloat162float(((const bf16*)p)[i]) : ((const float*)p)[i];
}
static __device__ __forceinline__ short b2s(bf16 b) {
  short s; __builtin_memcpy(&s, &b, 2); return s;
}

// Input dtype detector: in bf16 world, low 16 bits of each 32-bit word of
// emb_table hold a bf16 with |v|<2 -> bit14 == 0 always. In f32 world they
// hold mantissa bits -> bit14 ~ Bernoulli(0.5). 4096 samples, margin >30 sigma.
__global__ void detect_dtype(const unsigned short* __restrict__ e2, int* __restrict__ flag) {
  __shared__ int red[4];
  int tid = threadIdx.x;
  int ones = 0;
#pragma unroll
  for (int s = 0; s < 16; ++s) {
    int w = tid * 16 + s;             // 32-bit word index 0..4095 (16 KB, in-bounds both worlds)
    ones += (e2[2 * w] >> 14) & 1;    // bit14 of the low half
  }
  for (int off = 32; off > 0; off >>= 1) ones += __shfl_down(ones, off, 64);
  if ((tid & 63) == 0) red[tid >> 6] = ones;
  __syncthreads();
  if (tid == 0) {
    int tot = red[0] + red[1] + red[2] + red[3];
    *flag = (tot < 1024) ? 1 : 0;     // 1 = bf16 inputs, 0 = f32 inputs
  }
}

// Stage a 128x32 bf16 tile (row-major, ld elements; ld%8==0, base 16B-aligned)
// into LDS [128][32] shorts. Plain register staging.
static __device__ __forceinline__ void stage128x32(const bf16* gbase, int ld, short* lds) {
  const int r_ = threadIdx.x >> 1;
  const int half_ = threadIdx.x & 1;
  const short* g = (const short*)gbase + (size_t)r_ * ld + half_ * 16;
  short* d = lds + r_ * 32 + half_ * 16;
  uint4 v0 = *(const uint4*)(g);
  uint4 v1 = *(const uint4*)(g + 8);
  *(uint4*)(d) = v0;
  *(uint4*)(d + 8) = v1;
}
// Same, but source is f32 (ld%4==0 -> rows 16B-aligned); converts to bf16.
static __device__ __forceinline__ void stage128x32_f32(const float* gbase, int ld, short* lds) {
  const int r_ = threadIdx.x >> 1;
  const int half_ = threadIdx.x & 1;
  const float* g = gbase + (size_t)r_ * ld + half_ * 16;
  short* d = lds + r_ * 32 + half_ * 16;
#pragma unroll
  for (int q = 0; q < 4; ++q) {
    float4 v = *(const float4*)(g + 4 * q);
    short4 sv = make_short4(b2s(__float2bfloat16(v.x)), b2s(__float2bfloat16(v.y)),
                            b2s(__float2bfloat16(v.z)), b2s(__float2bfloat16(v.w)));
    *(short4*)(d + 4 * q) = sv;
  }
}

// C[m][n] = sum_k A[m][k] * W[n][k] (+ bias[n]); M,N multiples of 128, K of 32.
// A is always ws bf16. W/bias: if rawp!=null they are RAW inputs whose dtype
// follows *rawp (1=bf16, 0=f32). outmode=1: write d_out in *rawp's format
// (Cf/Cb alias d_out); outmode=0: write whichever of Cf/Cb is non-null.
__global__ __launch_bounds__(256) void gemm_bt(
    const bf16* __restrict__ A, int lda,
    const void* __restrict__ W, int ldw,
    const void* __restrict__ bias,
    float* __restrict__ Cf, bf16* __restrict__ Cb, int ldc, int K,
    const int* __restrict__ rawp, int outmode) {
  __shared__ __align__(16) short As[128 * 32];
  __shared__ __align__(16) short Bs[128 * 32];
  const int isb = rawp ? *rawp : 1;
  const int n0 = blockIdx.x * 128, m0 = blockIdx.y * 128;
  const int lane = threadIdx.x & 63, wv = threadIdx.x >> 6;
  const int wm = (wv & 1) * 64, wn = (wv >> 1) * 64;
  f32x4 acc[4][4];
#pragma unroll
  for (int i = 0; i < 4; ++i)
#pragma unroll
    for (int j = 0; j < 4; ++j) acc[i][j] = (f32x4){0.f, 0.f, 0.f, 0.f};
  for (int k0 = 0; k0 < K; k0 += 32) {
    stage128x32(A + (size_t)m0 * lda + k0, lda, As);
    if (isb) stage128x32((const bf16*)W + (size_t)n0 * ldw + k0, ldw, Bs);
    else stage128x32_f32((const float*)W + (size_t)n0 * ldw + k0, ldw, Bs);
    __syncthreads();
    const int krd = (lane >> 4) * 8;
    const int rsel = lane & 15;
    frag16 af[4], bfg[4];
#pragma unroll
    for (int i = 0; i < 4; ++i) af[i] = *(const frag16*)&As[(wm + i * 16 + rsel) * 32 + krd];
#pragma unroll
    for (int i = 0; i < 4; ++i) bfg[i] = *(const frag16*)&Bs[(wn + i * 16 + rsel) * 32 + krd];
#pragma unroll
    for (int i = 0; i < 4; ++i)
#pragma unroll
      for (int j = 0; j < 4; ++j)
        acc[i][j] = __builtin_amdgcn_mfma_f32_16x16x32_bf16(af[i], bfg[j], acc[i][j], 0, 0, 0);
    __syncthreads();
  }
  const int rq = (lane >> 4) * 4, cq = lane & 15;
#pragma unroll
  for (int j = 0; j < 4; ++j) {
    int cidx = n0 + wn + j * 16 + cq;
    float bv = bias ? ldraw(bias, cidx, isb) : 0.f;
#pragma unroll
    for (int i = 0; i < 4; ++i) {
      int rbase = m0 + wm + i * 16 + rq;
#pragma unroll
      for (int r = 0; r < 4; ++r) {
        float v = acc[i][j][r] + bv;
        size_t idx = (size_t)(rbase + r) * ldc + cidx;
        if (outmode) {
          if (isb) Cb[idx] = __float2bfloat16(v);
          else Cf[idx] = v;
        } else {
          if (Cf) Cf[idx] = v;
          if (Cb) Cb[idx] = __float2bfloat16(v);
        }
      }
    }
  }
}

// One LSTM timestep, one direction. A = [emb(x_t) | h_prev] (K=640, halves
// zero-padded 300->320), W = gate-interleaved Wcat (N=1280, n=4j+q).
__global__ __launch_bounds__(256) void lstm_step(
    const void* __restrict__ emb, const int* __restrict__ x,
    const bf16* __restrict__ Wcat, const float* __restrict__ bcat,
    bf16* __restrict__ hpad, float* __restrict__ cstate,
    bf16* __restrict__ Hout, int dir, int s, const int* __restrict__ flagp) {
  __shared__ __align__(16) char smem[32768];
  short* As = (short*)smem;
  short* Bs = (short*)(smem + 8192);
  float* epi = (float*)smem;  // reused after K-loop: 128 x 64 fp32
  const int isb = *flagp;
  const int tt = dir ? (T_ - 1 - s) : s;
  const int pb = s & 1;
  const bf16* Wd = Wcat + (size_t)dir * NP * KC;
  const bf16* hin = hpad + (size_t)(dir * 2 + pb) * B_ * HP;
  bf16* hout = hpad + (size_t)(dir * 2 + (1 - pb)) * B_ * HP;
  float* cs = cstate + (size_t)dir * B_ * HP;
  const int n0 = blockIdx.x * 128, m0 = blockIdx.y * 128;
  const int lane = threadIdx.x & 63, wv = threadIdx.x >> 6;
  const int wm = (wv & 1) * 64, wn = (wv >> 1) * 64;
  const int r_ = threadIdx.x >> 1;     // 0..127
  const int half_ = threadIdx.x & 1;   // 0..1
  const size_t xoff = (size_t)x[(m0 + r_) * T_ + tt] * (size_t)E_;  // elements
  short* arow = As + r_ * 32 + half_ * 16;

  f32x4 acc[4][4];
#pragma unroll
  for (int i = 0; i < 4; ++i)
#pragma unroll
    for (int j = 0; j < 4; ++j) acc[i][j] = (f32x4){0.f, 0.f, 0.f, 0.f};
  for (int k0 = 0; k0 < KC; k0 += 32) {
    if (k0 < HP) {
      // x-half: 300 % 4 == 0 so each 4-element chunk is fully valid or pad.
      if (isb) {
        const short* es = (const short*)emb;
#pragma unroll
        for (int g = 0; g < 4; ++g) {
          int cbase = k0 + half_ * 16 + 4 * g;
          short4 vv = make_short4(0, 0, 0, 0);
          if (cbase < E_) vv = *(const short4*)(es + xoff + cbase);
          *(short4*)(arow + 4 * g) = vv;
        }
      } else {
        const float* ef = (const float*)emb;
#pragma unroll
        for (int g = 0; g < 4; ++g) {
          int cbase = k0 + half_ * 16 + 4 * g;
          short4 vv = make_short4(0, 0, 0, 0);
          if (cbase < E_) {
            float4 f = *(const float4*)(ef + xoff + cbase);
            vv = make_short4(b2s(__float2bfloat16(f.x)), b2s(__float2bfloat16(f.y)),
                             b2s(__float2bfloat16(f.z)), b2s(__float2bfloat16(f.w)));
          }
          *(short4*)(arow + 4 * g) = vv;
        }
      }
    } else {
      stage128x32(hin + (size_t)m0 * HP + (k0 - HP), HP, As);
    }
    stage128x32(Wd + (size_t)n0 * KC + k0, KC, Bs);
    __syncthreads();
    const int krd = (lane >> 4) * 8;
    const int rsel = lane & 15;
    frag16 af[4], bfg[4];
#pragma unroll
    for (int i = 0; i < 4; ++i) af[i] = *(const frag16*)&As[(wm + i * 16 + rsel) * 32 + krd];
#pragma unroll
    for (int i = 0; i < 4; ++i) bfg[i] = *(const frag16*)&Bs[(wn + i * 16 + rsel) * 32 + krd];
#pragma unroll
    for (int i = 0; i < 4; ++i)
#pragma unroll
      for (int j = 0; j < 4; ++j)
        acc[i][j] = __builtin_amdgcn_mfma_f32_16x16x32_bf16(af[i], bfg[j], acc[i][j], 0, 0, 0);
    __syncthreads();
  }
  const int rq = (lane >> 4) * 4, cq = lane & 15;
#pragma unroll
  for (int p = 0; p < 2; ++p) {
    if (wn == p * 64) {
#pragma unroll
      for (int j = 0; j < 4; ++j) {
        int cl = j * 16 + cq;
        float bv = bcat[dir * NP + n0 + p * 64 + cl];
#pragma unroll
        for (int i = 0; i < 4; ++i) {
          int rl = wm + i * 16 + rq;
#pragma unroll
          for (int r = 0; r < 4; ++r) epi[(rl + r) * 64 + cl] = acc[i][j][r] + bv;
        }
      }
    }
    __syncthreads();
    int jbase = (n0 + p * 64) >> 2;
    for (int it = threadIdx.x; it < 128 * 16; it += 256) {
      int rl = it >> 4, jl = it & 15;
      int jg = jbase + jl;
      if (jg < H_) {
        const float* row = epi + rl * 64 + jl * 4;
        float iv = sigf(row[0]);
        float fv = sigf(row[1]);
        float gv = tanhfast(row[2]);
        float ov = sigf(row[3]);
        int b = m0 + rl;
        float c = fv * cs[(size_t)b * HP + jg] + iv * gv;
        float h = ov * tanhfast(c);
        cs[(size_t)b * HP + jg] = c;
        bf16 hb = __float2bfloat16(h);
        hout[(size_t)b * HP + jg] = hb;
        if (Hout) Hout[((size_t)tt * B_ + b) * H_ + jg] = hb;
      }
    }
    __syncthreads();
  }
}

// Build gate-interleaved padded weights + bias for both dirs (dtype-flexible).
__global__ void prep_wcat(const void* __restrict__ Wih_f, const void* __restrict__ Whh_f,
                          const void* __restrict__ bih_f, const void* __restrict__ bhh_f,
                          const void* __restrict__ Wih_b, const void* __restrict__ Whh_b,
                          const void* __restrict__ bih_b, const void* __restrict__ bhh_b,
                          bf16* __restrict__ Wcat, float* __restrict__ bcat,
                          const int* __restrict__ flagp) {
  int i = blockIdx.x * 256 + threadIdx.x;
  if (i >= 2 * NP * KC) return;
  const int isb = *flagp;
  int k = i % KC;
  int n = (i / KC) % NP;
  int dir = i / (KC * NP);
  int j = n >> 2, q = n & 3;
  const void* Wih = dir ? Wih_b : Wih_f;
  const void* Whh = dir ? Whh_b : Whh_f;
  float v = 0.f;
  if (j < H_) {
    int row = q * H_ + j;
    if (k < E_) v = ldraw(Wih, (size_t)row * E_ + k, isb);
    else if (k >= HP && k < HP + H_) v = ldraw(Whh, (size_t)row * H_ + (k - HP), isb);
  }
  Wcat[i] = __float2bfloat16(v);
  if (k == 0) {
    const void* bih = dir ? bih_b : bih_f;
    const void* bhh = dir ? bhh_b : bhh_f;
    bcat[dir * NP + n] =
        (j < H_) ? (ldraw(bih, q * H_ + j, isb) + ldraw(bhh, q * H_ + j, isb)) : 0.f;
  }
}

// Normalized label embeddings, K-padded 600->640 (dtype-flexible).
__global__ __launch_bounds__(256) void labelnorm(const void* __restrict__ L,
                                                 bf16* __restrict__ lnp,
                                                 const int* __restrict__ flagp) {
  int l = blockIdx.x, tid = threadIdx.x;
  const int isb = *flagp;
  __shared__ float red[4];
  float v[3];
  float ss = 0.f;
#pragma unroll
  for (int s = 0; s < 3; ++s) {
    int d = tid + 256 * s;
    v[s] = (d < 600) ? ldraw(L, (size_t)l * 600 + d, isb) : 0.f;
    ss += v[s] * v[s];
  }
  for (int off = 32; off > 0; off >>= 1) ss += __shfl_down(ss, off, 64);
  if ((tid & 63) == 0) red[tid >> 6] = ss;
  __syncthreads();
  float scale = 1.f / fmaxf(sqrtf(red[0] + red[1] + red[2] + red[3]), 1e-8f);
#pragma unroll
  for (int s = 0; s < 3; ++s) {
    int d = tid + 256 * s;
    if (d < KC) lnp[(size_t)l * KC + d] = __float2bfloat16(v[s] * scale);
  }
}

// After forward step t: Spf[b][d] += concat(hf_t, hb_t)[d] / ||concat||.
__global__ __launch_bounds__(256) void normacc(const bf16* __restrict__ hf,
                                               const bf16* __restrict__ Hb,
                                               float* __restrict__ Spf, int t) {
  int b = blockIdx.x * 4 + (threadIdx.x >> 6);
  int lane = threadIdx.x & 63;
  const bf16* hfb = hf + (size_t)b * HP;
  const bf16* hbb = Hb + ((size_t)t * B_ + b) * H_;
  float v[10];
  float ss = 0.f;
#pragma unroll
  for (int s = 0; s < 10; ++s) {
    int d = lane + 64 * s;
    float xv = 0.f;
    if (d < 300) xv = __bfloat162float(hfb[d]);
    else if (d < 600) xv = __bfloat162float(hbb[d - 300]);
    v[s] = xv;
    ss += xv * xv;
  }
#pragma unroll
  for (int off = 32; off > 0; off >>= 1) ss += __shfl_xor(ss, off, 64);
  float scale = 1.f / fmaxf(sqrtf(ss), 1e-8f);
#pragma unroll
  for (int s = 0; s < 10; ++s) {
    int d = lane + 64 * s;
    if (d < 600) Spf[(size_t)b * KC + d] += v[s] * scale;
  }
}

__global__ void spcvt(const float* __restrict__ Spf, bf16* __restrict__ Sp) {
  int i = blockIdx.x * 256 + threadIdx.x;
  Sp[i] = __float2bfloat16(Spf[i]);
}

// Wt[l][n][k] = ggc_weight[l][k][n] (dtype-flexible source)
__global__ void transpose_ggc(const void* __restrict__ W, bf16* __restrict__ Wt,
                              const int* __restrict__ flagp) {
  int i = blockIdx.x * 256 + threadIdx.x;
  const int isb = *flagp;
  int k = i & 1023, n = (i >> 10) & 1023, l = i >> 20;
  size_t src = ((size_t)l << 20) | ((size_t)k << 10) | (size_t)n;
  Wt[i] = __float2bfloat16(ldraw(W, src, isb));
}

__global__ void zero_u4(uint4* __restrict__ p, int n16) {
  int i = blockIdx.x * 256 + threadIdx.x;
  if (i < n16) p[i] = make_uint4(0u, 0u, 0u, 0u);
}

__global__ void scatter_add(const int* __restrict__ ei, const float* __restrict__ m1,
                            float* __restrict__ agg) {
  int e = blockIdx.x;
  int s = ei[e], d = ei[NE_ + e];
  const float* srow = m1 + (size_t)s * C_;
  float* drow = agg + (size_t)d * C_;
  int c = threadIdx.x * 4;
  float4 v = *(const float4*)(srow + c);
  atomicAdd(drow + c + 0, v.x);
  atomicAdd(drow + c + 1, v.y);
  atomicAdd(drow + c + 2, v.z);
  atomicAdd(drow + c + 3, v.w);
}

__global__ void f2b(const float* __restrict__ s, bf16* __restrict__ d, int n) {
  int i = blockIdx.x * 256 + threadIdx.x;
  if (i < n) d[i] = __float2bfloat16(s[i]);
}

__global__ void gru_ew(const float* __restrict__ gi, const float* __restrict__ gh,
                       float* __restrict__ h, bf16* __restrict__ hb16) {
  int i = blockIdx.x * 256 + threadIdx.x;
  int b = i >> 10, j = i & 1023;
  const float* gib = gi + (size_t)b * 3072;
  const float* ghb = gh + (size_t)b * 3072;
  float r = sigf(gib[j] + ghb[j]);
  float z = sigf(gib[1024 + j] + ghb[1024 + j]);
  float n = tanhfast(gib[2048 + j] + r * ghb[2048 + j]);
  float hv = (1.f - z) * n + z * h[i];
  h[i] = hv;
  hb16[i] = __float2bfloat16(hv);
}

__global__ void sentinel(bf16* __restrict__ o, int n, float v) {
  int i = blockIdx.x * 256 + threadIdx.x;
  if (i < n) o[i] = __float2bfloat16(v);
}

extern "C" void kernel_launch(void* const* d_in, const int* in_sizes, int n_in,
                              void* d_out, int out_size, void* d_ws, size_t ws_size,
                              hipStream_t stream) {
  const int* x = (const int*)d_in[0];
  const int* ei = (const int*)d_in[1];
  const void* emb = d_in[2];
  const void* Wih_f = d_in[3];
  const void* Whh_f = d_in[4];
  const void* bih_f = d_in[5];
  const void* bhh_f = d_in[6];
  const void* Wih_b = d_in[7];
  const void* Whh_b = d_in[8];
  const void* bih_b = d_in[9];
  const void* bhh_b = d_in[10];
  const void* label = d_in[11];
  const void* ggcw = d_in[12];
  const void* gWih = d_in[13];
  const void* gWhh = d_in[14];
  const void* gbih = d_in[15];
  const void* gbhh = d_in[16];
  const void* projW = d_in[17];
  const void* projb = d_in[18];
  (void)in_sizes; (void)n_in;

  const size_t NEED = (size_t)112 * 1024 * 1024;
  if (ws_size < NEED) {
    float v = 100.f + (float)(ws_size >> 24);
    sentinel<<<(out_size + 255) / 256, 256, 0, stream>>>((bf16*)d_out, out_size, v);
    return;
  }

  char* w = (char*)d_ws;
  size_t off = 0;
  auto alloc = [&](size_t bytes) {
    char* p = w + off;
    off += (bytes + 255) & ~(size_t)255;
    return p;
  };
  // ---- persistent (~11.4 MB) ----
  int* dflag = (int*)alloc(256);
  bf16* Wcat = (bf16*)alloc((size_t)2 * NP * KC * 2);
  float* bcat = (float*)alloc((size_t)2 * NP * 4);
  bf16* lnp = (bf16*)alloc((size_t)C_ * KC * 2);
  bf16* ggct = (bf16*)alloc((size_t)2 * C_ * C_ * 2);
  bf16* Sp = (bf16*)alloc((size_t)B_ * KC * 2);
  const size_t phase_base = off;
  // ---- phase 1 (LSTM): peak ~106 MB ----
  float* Spf = (float*)alloc((size_t)B_ * KC * 4);
  bf16* hpad = (bf16*)alloc((size_t)4 * B_ * HP * 2);
  float* cst = (float*)alloc((size_t)2 * B_ * HP * 4);
  bf16* Hb = (bf16*)alloc((size_t)T_ * B_ * H_ * 2);
  // ---- phase 2 (graph): aliases phase 1 ----
  off = phase_base;
  float* hbuf = (float*)alloc((size_t)B_ * C_ * 4);
  bf16* hb16 = (bf16*)alloc((size_t)B_ * C_ * 2);
  float* m1 = (float*)alloc((size_t)B_ * C_ * 4);
  float* agg = (float*)alloc((size_t)B_ * C_ * 4);
  bf16* aggb = (bf16*)alloc((size_t)B_ * C_ * 2);
  float* gi = (float*)alloc((size_t)B_ * 3072 * 4);
  float* gh = (float*)alloc((size_t)B_ * 3072 * 4);

  // ---- dtype detection + prep ----
  detect_dtype<<<1, 256, 0, stream>>>((const unsigned short*)emb, dflag);
  prep_wcat<<<(2 * NP * KC) / 256, 256, 0, stream>>>(Wih_f, Whh_f, bih_f, bhh_f,
                                                     Wih_b, Whh_b, bih_b, bhh_b, Wcat, bcat, dflag);
  labelnorm<<<C_, 256, 0, stream>>>(label, lnp, dflag);
  transpose_ggc<<<(2 * C_ * C_) / 256, 256, 0, stream>>>(ggcw, ggct, dflag);
  zero_u4<<<(4 * B_ * HP * 2 / 16 + 255) / 256, 256, 0, stream>>>((uint4*)hpad, 4 * B_ * HP * 2 / 16);
  zero_u4<<<(2 * B_ * HP * 4 / 16 + 255) / 256, 256, 0, stream>>>((uint4*)cst, 2 * B_ * HP * 4 / 16);
  zero_u4<<<(B_ * KC * 4 / 16 + 255) / 256, 256, 0, stream>>>((uint4*)Spf, B_ * KC * 4 / 16);

  // ---- phase 1a: backward LSTM (stores Hb) ----
  for (int s = 0; s < T_; ++s)
    lstm_step<<<dim3(NP / 128, B_ / 128), 256, 0, stream>>>(emb, x, Wcat, bcat, hpad, cst,
                                                            Hb, 1, s, dflag);
  // ---- phase 1b: forward LSTM streamed + fused norm-accumulate ----
  for (int s = 0; s < T_; ++s) {
    lstm_step<<<dim3(NP / 128, B_ / 128), 256, 0, stream>>>(emb, x, Wcat, bcat, hpad, cst,
                                                            nullptr, 0, s, dflag);
    const bf16* hfbuf = hpad + (size_t)(1 - (s & 1)) * B_ * HP;
    normacc<<<B_ / 4, 256, 0, stream>>>(hfbuf, Hb, Spf, s);
  }
  spcvt<<<(B_ * KC) / 256, 256, 0, stream>>>(Spf, Sp);

  // ---- phase 2: label scores + GatedGraphConv + proj ----
  gemm_bt<<<dim3(C_ / 128, B_ / 128), 256, 0, stream>>>(Sp, KC, lnp, KC, nullptr,
                                                        hbuf, hb16, C_, KC, nullptr, 0);
  for (int l = 0; l < 2; ++l) {
    gemm_bt<<<dim3(C_ / 128, B_ / 128), 256, 0, stream>>>(hb16, C_, ggct + (size_t)l * C_ * C_, C_,
                                                          nullptr, m1, nullptr, C_, C_, nullptr, 0);
    zero_u4<<<(B_ * C_ * 4 / 16 + 255) / 256, 256, 0, stream>>>((uint4*)agg, B_ * C_ * 4 / 16);
    scatter_add<<<NE_, 256, 0, stream>>>(ei, m1, agg);
    f2b<<<(B_ * C_) / 256, 256, 0, stream>>>(agg, aggb, B_ * C_);
    gemm_bt<<<dim3(3072 / 128, B_ / 128), 256, 0, stream>>>(aggb, C_, gWih, C_, gbih,
                                                            gi, nullptr, 3072, C_, dflag, 0);
    gemm_bt<<<dim3(3072 / 128, B_ / 128), 256, 0, stream>>>(hb16, C_, gWhh, C_, gbhh,
                                                            gh, nullptr, 3072, C_, dflag, 0);
    gru_ew<<<(B_ * C_) / 256, 256, 0, stream>>>(gi, gh, hbuf, hb16);
  }
  // final projection: output format follows detected input dtype
  gemm_bt<<<dim3(C_ / 128, B_ / 128), 256, 0, stream>>>(hb16, C_, projW, C_, projb,
                                                        (float*)d_out, (bf16*)d_out, C_, C_,
                                                        dflag, 1);
}

// Round 8
// 3558.406 us; speedup vs baseline: 1.7298x; 1.7298x over previous
//
#include <hip/hip_runtime.h>
#include <hip/hip_bf16.h>
#include <stdint.h>

typedef __hip_bfloat16 bf16;
typedef __attribute__((ext_vector_type(8))) short frag16;
typedef __attribute__((ext_vector_type(4))) float f32x4;

#define B_ 2048
#define T_ 64
#define E_ 300
#define H_ 300
#define C_ 1024
#define NE_ 65536
#define HP 320     // padded E/H half of concat-K
#define KC 640     // padded concat K (320 x + 320 h)
#define NP 1280    // padded 4H, gate-interleaved n = 4*j + q

static __device__ __forceinline__ float sigf(float x) {
  x = fminf(fmaxf(x, -30.f), 30.f);
  return 1.f / (1.f + __expf(-x));
}
static __device__ __forceinline__ float tanhfast(float x) {
  x = fminf(fmaxf(x, -15.f), 15.f);
  float e = __expf(2.f * x);
  return (e - 1.f) / (e + 1.f);
}
static __device__ __forceinline__ float ldraw(const void* p, size_t i, int isb) {
  return isb ? __bfloat162float(((const bf16*)p)[i]) : ((const float*)p)[i];
}
static __device__ __forceinline__ short b2s(bf16 b) {
  short s; __builtin_memcpy(&s, &b, 2); return s;
}

// Input dtype detector (verified working in R7): bit14 of low half-word is 0
// in bf16 world (|v|<2), ~Bernoulli(0.5) in f32 world (mantissa bits).
__global__ void detect_dtype(const unsigned short* __restrict__ e2, int* __restrict__ flag) {
  __shared__ int red[4];
  int tid = threadIdx.x;
  int ones = 0;
#pragma unroll
  for (int s = 0; s < 16; ++s) ones += (e2[2 * (tid * 16 + s)] >> 14) & 1;
  for (int off = 32; off > 0; off >>= 1) ones += __shfl_down(ones, off, 64);
  if ((tid & 63) == 0) red[tid >> 6] = ones;
  __syncthreads();
  if (tid == 0) {
    int tot = red[0] + red[1] + red[2] + red[3];
    *flag = (tot < 1024) ? 1 : 0;  // 1 = bf16 inputs, 0 = f32 inputs
  }
}

// Stage a 128x32 bf16 tile into LDS [128][32] shorts (register staging).
static __device__ __forceinline__ void stage128x32(const bf16* gbase, int ld, short* lds) {
  const int r_ = threadIdx.x >> 1;
  const int half_ = threadIdx.x & 1;
  const short* g = (const short*)gbase + (size_t)r_ * ld + half_ * 16;
  short* d = lds + r_ * 32 + half_ * 16;
  uint4 v0 = *(const uint4*)(g);
  uint4 v1 = *(const uint4*)(g + 8);
  *(uint4*)(d) = v0;
  *(uint4*)(d + 8) = v1;
}
// Same from f32 source, converting to bf16.
static __device__ __forceinline__ void stage128x32_f32(const float* gbase, int ld, short* lds) {
  const int r_ = threadIdx.x >> 1;
  const int half_ = threadIdx.x & 1;
  const float* g = gbase + (size_t)r_ * ld + half_ * 16;
  short* d = lds + r_ * 32 + half_ * 16;
#pragma unroll
  for (int q = 0; q < 4; ++q) {
    float4 v = *(const float4*)(g + 4 * q);
    *(short4*)(d + 4 * q) = make_short4(b2s(__float2bfloat16(v.x)), b2s(__float2bfloat16(v.y)),
                                        b2s(__float2bfloat16(v.z)), b2s(__float2bfloat16(v.w)));
  }
}
// Stage a 64x32 bf16 tile (for the lstm A-tile).
static __device__ __forceinline__ void stage64x32(const bf16* gbase, int ld, short* lds) {
  const int r_ = threadIdx.x >> 2;
  const int q_ = threadIdx.x & 3;
  const short* g = (const short*)gbase + (size_t)r_ * ld + q_ * 8;
  *(uint4*)(lds + r_ * 32 + q_ * 8) = *(const uint4*)g;
}

// C[m][n] = sum_k A[m][k]*W[n][k] (+bias[n]); M,N mult of 128, K of 32.
// A: ws bf16. W/bias raw iff rawp!=null (dtype *rawp). outmode=1: d_out in
// raw dtype (Cf/Cb alias d_out).
__global__ __launch_bounds__(256) void gemm_bt(
    const bf16* __restrict__ A, int lda,
    const void* __restrict__ W, int ldw,
    const void* __restrict__ bias,
    float* __restrict__ Cf, bf16* __restrict__ Cb, int ldc, int K,
    const int* __restrict__ rawp, int outmode) {
  __shared__ __align__(16) short As[128 * 32];
  __shared__ __align__(16) short Bs[128 * 32];
  const int isb = rawp ? *rawp : 1;
  const int n0 = blockIdx.x * 128, m0 = blockIdx.y * 128;
  const int lane = threadIdx.x & 63, wv = threadIdx.x >> 6;
  const int wm = (wv & 1) * 64, wn = (wv >> 1) * 64;
  f32x4 acc[4][4];
#pragma unroll
  for (int i = 0; i < 4; ++i)
#pragma unroll
    for (int j = 0; j < 4; ++j) acc[i][j] = (f32x4){0.f, 0.f, 0.f, 0.f};
  for (int k0 = 0; k0 < K; k0 += 32) {
    stage128x32(A + (size_t)m0 * lda + k0, lda, As);
    if (isb) stage128x32((const bf16*)W + (size_t)n0 * ldw + k0, ldw, Bs);
    else stage128x32_f32((const float*)W + (size_t)n0 * ldw + k0, ldw, Bs);
    __syncthreads();
    const int krd = (lane >> 4) * 8;
    const int rsel = lane & 15;
    frag16 af[4], bfg[4];
#pragma unroll
    for (int i = 0; i < 4; ++i) af[i] = *(const frag16*)&As[(wm + i * 16 + rsel) * 32 + krd];
#pragma unroll
    for (int i = 0; i < 4; ++i) bfg[i] = *(const frag16*)&Bs[(wn + i * 16 + rsel) * 32 + krd];
#pragma unroll
    for (int i = 0; i < 4; ++i)
#pragma unroll
      for (int j = 0; j < 4; ++j)
        acc[i][j] = __builtin_amdgcn_mfma_f32_16x16x32_bf16(af[i], bfg[j], acc[i][j], 0, 0, 0);
    __syncthreads();
  }
  const int rq = (lane >> 4) * 4, cq = lane & 15;
#pragma unroll
  for (int j = 0; j < 4; ++j) {
    int cidx = n0 + wn + j * 16 + cq;
    float bv = bias ? ldraw(bias, cidx, isb) : 0.f;
#pragma unroll
    for (int i = 0; i < 4; ++i) {
      int rbase = m0 + wm + i * 16 + rq;
#pragma unroll
      for (int r = 0; r < 4; ++r) {
        float v = acc[i][j][r] + bv;
        size_t idx = (size_t)(rbase + r) * ldc + cidx;
        if (outmode) {
          if (isb) Cb[idx] = __float2bfloat16(v);
          else Cf[idx] = v;
        } else {
          if (Cf) Cf[idx] = v;
          if (Cb) Cb[idx] = __float2bfloat16(v);
        }
      }
    }
  }
}

// One b-row of the norm-accumulate: Spf[b] += concat(hf,hb)/||.||
static __device__ __forceinline__ void normacc_row(const bf16* hfb, const bf16* hbb,
                                                   float* Spf, int b, int lane) {
  float v[10];
  float ss = 0.f;
#pragma unroll
  for (int s = 0; s < 10; ++s) {
    int d = lane + 64 * s;
    float xv = 0.f;
    if (d < 300) xv = __bfloat162float(hfb[d]);
    else if (d < 600) xv = __bfloat162float(hbb[d - 300]);
    v[s] = xv;
    ss += xv * xv;
  }
#pragma unroll
  for (int off = 32; off > 0; off >>= 1) ss += __shfl_xor(ss, off, 64);
  float scale = 1.f / fmaxf(sqrtf(ss), 1e-8f);
#pragma unroll
  for (int s = 0; s < 10; ++s) {
    int d = lane + 64 * s;
    if (d < 600) Spf[(size_t)b * KC + d] += v[s] * scale;
  }
}

// One LSTM timestep. 128(N)x64(M) tile -> 320 blocks (vs 160 at 128x128).
// Fwd dispatches use gridDim.z=2: z=1 blocks fold the PREVIOUS step's h into
// Spf (hin is read-only for both z-planes -> race-free).
__global__ __launch_bounds__(256) void lstm_step(
    const void* __restrict__ emb, const int* __restrict__ x,
    const bf16* __restrict__ Wcat, const float* __restrict__ bcat,
    bf16* __restrict__ hpad, float* __restrict__ cstate,
    bf16* __restrict__ Hb, float* __restrict__ Spf,
    int dir, int s, const int* __restrict__ flagp) {
  __shared__ __align__(16) char smem[16384];
  short* As = (short*)smem;            // 64x32 = 4 KB
  short* Bs = (short*)(smem + 4096);   // 128x32 = 8 KB
  float* epi = (float*)smem;           // reused: 64x64 fp32 = 16 KB
  const int tt = dir ? (T_ - 1 - s) : s;
  const int pb = s & 1;
  const bf16* hin = hpad + (size_t)(dir * 2 + pb) * B_ * HP;

  if (blockIdx.z == 1) {  // fused normacc for t = s-1 (fwd only)
    if (dir == 0 && s >= 1) {
      int bid = blockIdx.x + gridDim.x * blockIdx.y;  // 0..319
      int lane = threadIdx.x & 63, wv = threadIdx.x >> 6;
#pragma unroll
      for (int rep = 0; rep < 2; ++rep) {
        int b = bid * 4 + wv + 1280 * rep;
        if (b < B_)
          normacc_row(hin + (size_t)b * HP, Hb + ((size_t)(s - 1) * B_ + b) * H_, Spf, b, lane);
      }
    }
    return;
  }

  const int isb = *flagp;
  const bf16* Wd = Wcat + (size_t)dir * NP * KC;
  bf16* hout = hpad + (size_t)(dir * 2 + (1 - pb)) * B_ * HP;
  float* cs = cstate + (size_t)dir * B_ * HP;
  const int n0 = blockIdx.x * 128, m0 = blockIdx.y * 64;
  const int lane = threadIdx.x & 63, wv = threadIdx.x >> 6;
  const int wm = (wv & 1) * 32, wn = (wv >> 1) * 64;
  // x-half gather geometry: thread -> (row 0..63, 8-elem chunk 0..3)
  const int r_ = threadIdx.x >> 2;
  const int q_ = threadIdx.x & 3;
  const size_t xoff = (size_t)x[(m0 + r_) * T_ + tt] * (size_t)E_;
  short* arow = As + r_ * 32 + q_ * 8;

  f32x4 acc[2][4];
#pragma unroll
  for (int i = 0; i < 2; ++i)
#pragma unroll
    for (int j = 0; j < 4; ++j) acc[i][j] = (f32x4){0.f, 0.f, 0.f, 0.f};
  for (int k0 = 0; k0 < KC; k0 += 32) {
    if (k0 < HP) {
      // 2 short4 chunks/thread; 300%4==0 -> chunk fully valid or fully pad.
      if (isb) {
        const short* es = (const short*)emb;
#pragma unroll
        for (int g = 0; g < 2; ++g) {
          int cbase = k0 + q_ * 8 + 4 * g;
          short4 vv = make_short4(0, 0, 0, 0);
          if (cbase < E_) vv = *(const short4*)(es + xoff + cbase);
          *(short4*)(arow + 4 * g) = vv;
        }
      } else {
        const float* ef = (const float*)emb;
#pragma unroll
        for (int g = 0; g < 2; ++g) {
          int cbase = k0 + q_ * 8 + 4 * g;
          short4 vv = make_short4(0, 0, 0, 0);
          if (cbase < E_) {
            float4 f = *(const float4*)(ef + xoff + cbase);
            vv = make_short4(b2s(__float2bfloat16(f.x)), b2s(__float2bfloat16(f.y)),
                             b2s(__float2bfloat16(f.z)), b2s(__float2bfloat16(f.w)));
          }
          *(short4*)(arow + 4 * g) = vv;
        }
      }
    } else {
      stage64x32(hin + (size_t)m0 * HP + (k0 - HP), HP, As);
    }
    stage128x32(Wd + (size_t)n0 * KC + k0, KC, Bs);
    __syncthreads();
    const int krd = (lane >> 4) * 8;
    const int rsel = lane & 15;
    frag16 af[2], bfg[4];
#pragma unroll
    for (int i = 0; i < 2; ++i) af[i] = *(const frag16*)&As[(wm + i * 16 + rsel) * 32 + krd];
#pragma unroll
    for (int i = 0; i < 4; ++i) bfg[i] = *(const frag16*)&Bs[(wn + i * 16 + rsel) * 32 + krd];
#pragma unroll
    for (int i = 0; i < 2; ++i)
#pragma unroll
      for (int j = 0; j < 4; ++j)
        acc[i][j] = __builtin_amdgcn_mfma_f32_16x16x32_bf16(af[i], bfg[j], acc[i][j], 0, 0, 0);
    __syncthreads();
  }
  const int rq = (lane >> 4) * 4, cq = lane & 15;
#pragma unroll
  for (int p = 0; p < 2; ++p) {
    if (wn == p * 64) {
#pragma unroll
      for (int j = 0; j < 4; ++j) {
        int cl = j * 16 + cq;
        float bv = bcat[dir * NP + n0 + p * 64 + cl];
#pragma unroll
        for (int i = 0; i < 2; ++i) {
          int rl = wm + i * 16 + rq;
#pragma unroll
          for (int r = 0; r < 4; ++r) epi[(rl + r) * 64 + cl] = acc[i][j][r] + bv;
        }
      }
    }
    __syncthreads();
    int jbase = (n0 + p * 64) >> 2;
    for (int it = threadIdx.x; it < 64 * 16; it += 256) {
      int rl = it >> 4, jl = it & 15;
      int jg = jbase + jl;
      if (jg < H_) {
        const float* row = epi + rl * 64 + jl * 4;
        float iv = sigf(row[0]);
        float fv = sigf(row[1]);
        float gv = tanhfast(row[2]);
        float ov = sigf(row[3]);
        int b = m0 + rl;
        float c = fv * cs[(size_t)b * HP + jg] + iv * gv;
        float h = ov * tanhfast(c);
        cs[(size_t)b * HP + jg] = c;
        bf16 hb = __float2bfloat16(h);
        hout[(size_t)b * HP + jg] = hb;
        if (dir) Hb[((size_t)tt * B_ + b) * H_ + jg] = hb;
      }
    }
    __syncthreads();
  }
}

// Build gate-interleaved padded weights + bias for both dirs (dtype-flexible).
__global__ void prep_wcat(const void* __restrict__ Wih_f, const void* __restrict__ Whh_f,
                          const void* __restrict__ bih_f, const void* __restrict__ bhh_f,
                          const void* __restrict__ Wih_b, const void* __restrict__ Whh_b,
                          const void* __restrict__ bih_b, const void* __restrict__ bhh_b,
                          bf16* __restrict__ Wcat, float* __restrict__ bcat,
                          const int* __restrict__ flagp) {
  int i = blockIdx.x * 256 + threadIdx.x;
  if (i >= 2 * NP * KC) return;
  const int isb = *flagp;
  int k = i % KC;
  int n = (i / KC) % NP;
  int dir = i / (KC * NP);
  int j = n >> 2, q = n & 3;
  const void* Wih = dir ? Wih_b : Wih_f;
  const void* Whh = dir ? Whh_b : Whh_f;
  float v = 0.f;
  if (j < H_) {
    int row = q * H_ + j;
    if (k < E_) v = ldraw(Wih, (size_t)row * E_ + k, isb);
    else if (k >= HP && k < HP + H_) v = ldraw(Whh, (size_t)row * H_ + (k - HP), isb);
  }
  Wcat[i] = __float2bfloat16(v);
  if (k == 0) {
    const void* bih = dir ? bih_b : bih_f;
    const void* bhh = dir ? bhh_b : bhh_f;
    bcat[dir * NP + n] =
        (j < H_) ? (ldraw(bih, q * H_ + j, isb) + ldraw(bhh, q * H_ + j, isb)) : 0.f;
  }
}

// Normalized label embeddings, K-padded 600->640 (dtype-flexible).
__global__ __launch_bounds__(256) void labelnorm(const void* __restrict__ L,
                                                 bf16* __restrict__ lnp,
                                                 const int* __restrict__ flagp) {
  int l = blockIdx.x, tid = threadIdx.x;
  const int isb = *flagp;
  __shared__ float red[4];
  float v[3];
  float ss = 0.f;
#pragma unroll
  for (int s = 0; s < 3; ++s) {
    int d = tid + 256 * s;
    v[s] = (d < 600) ? ldraw(L, (size_t)l * 600 + d, isb) : 0.f;
    ss += v[s] * v[s];
  }
  for (int off = 32; off > 0; off >>= 1) ss += __shfl_down(ss, off, 64);
  if ((tid & 63) == 0) red[tid >> 6] = ss;
  __syncthreads();
  float scale = 1.f / fmaxf(sqrtf(red[0] + red[1] + red[2] + red[3]), 1e-8f);
#pragma unroll
  for (int s = 0; s < 3; ++s) {
    int d = tid + 256 * s;
    if (d < KC) lnp[(size_t)l * KC + d] = __float2bfloat16(v[s] * scale);
  }
}

// Standalone normacc (trailing t=63 only).
__global__ __launch_bounds__(256) void normacc(const bf16* __restrict__ hf,
                                               const bf16* __restrict__ Hb,
                                               float* __restrict__ Spf, int t) {
  int b = blockIdx.x * 4 + (threadIdx.x >> 6);
  normacc_row(hf + (size_t)b * HP, Hb + ((size_t)t * B_ + b) * H_, Spf, b, threadIdx.x & 63);
}

__global__ void spcvt(const float* __restrict__ Spf, bf16* __restrict__ Sp) {
  int i = blockIdx.x * 256 + threadIdx.x;
  Sp[i] = __float2bfloat16(Spf[i]);
}

// Wt[l][n][k] = ggc_weight[l][k][n] (dtype-flexible source)
__global__ void transpose_ggc(const void* __restrict__ W, bf16* __restrict__ Wt,
                              const int* __restrict__ flagp) {
  int i = blockIdx.x * 256 + threadIdx.x;
  const int isb = *flagp;
  int k = i & 1023, n = (i >> 10) & 1023, l = i >> 20;
  size_t src = ((size_t)l << 20) | ((size_t)k << 10) | (size_t)n;
  Wt[i] = __float2bfloat16(ldraw(W, src, isb));
}

__global__ void zero_u4(uint4* __restrict__ p, int n16) {
  int i = blockIdx.x * 256 + threadIdx.x;
  if (i < n16) p[i] = make_uint4(0u, 0u, 0u, 0u);
}

// Dense adjacency counts: cnt[d][s] = #edges s->d (int atomics, 65536 total).
__global__ void edge_cnt(const int* __restrict__ ei, int* __restrict__ cnt) {
  int e = blockIdx.x * 256 + threadIdx.x;
  if (e < NE_) {
    int s = ei[e], d = ei[NE_ + e];
    atomicAdd(&cnt[(size_t)d * B_ + s], 1);
  }
}
__global__ void cnt2bf(const int* __restrict__ cnt, bf16* __restrict__ A) {
  int i = blockIdx.x * 256 + threadIdx.x;  // 4M
  A[i] = __float2bfloat16((float)cnt[i]);
}

__global__ void gru_ew(const float* __restrict__ gi, const float* __restrict__ gh,
                       float* __restrict__ h, bf16* __restrict__ hb16) {
  int i = blockIdx.x * 256 + threadIdx.x;
  int b = i >> 10, j = i & 1023;
  const float* gib = gi + (size_t)b * 3072;
  const float* ghb = gh + (size_t)b * 3072;
  float r = sigf(gib[j] + ghb[j]);
  float z = sigf(gib[1024 + j] + ghb[1024 + j]);
  float n = tanhfast(gib[2048 + j] + r * ghb[2048 + j]);
  float hv = (1.f - z) * n + z * h[i];
  h[i] = hv;
  hb16[i] = __float2bfloat16(hv);
}

__global__ void sentinel(bf16* __restrict__ o, int n, float v) {
  int i = blockIdx.x * 256 + threadIdx.x;
  if (i < n) o[i] = __float2bfloat16(v);
}

extern "C" void kernel_launch(void* const* d_in, const int* in_sizes, int n_in,
                              void* d_out, int out_size, void* d_ws, size_t ws_size,
                              hipStream_t stream) {
  const int* x = (const int*)d_in[0];
  const int* ei = (const int*)d_in[1];
  const void* emb = d_in[2];
  const void* Wih_f = d_in[3];
  const void* Whh_f = d_in[4];
  const void* bih_f = d_in[5];
  const void* bhh_f = d_in[6];
  const void* Wih_b = d_in[7];
  const void* Whh_b = d_in[8];
  const void* bih_b = d_in[9];
  const void* bhh_b = d_in[10];
  const void* label = d_in[11];
  const void* ggcw = d_in[12];
  const void* gWih = d_in[13];
  const void* gWhh = d_in[14];
  const void* gbih = d_in[15];
  const void* gbhh = d_in[16];
  const void* projW = d_in[17];
  const void* projb = d_in[18];
  (void)in_sizes; (void)n_in;

  const size_t NEED = (size_t)112 * 1024 * 1024;
  if (ws_size < NEED) {
    float v = 100.f + (float)(ws_size >> 24);
    sentinel<<<(out_size + 255) / 256, 256, 0, stream>>>((bf16*)d_out, out_size, v);
    return;
  }

  char* w = (char*)d_ws;
  size_t off = 0;
  auto alloc = [&](size_t bytes) {
    char* p = w + off;
    off += (bytes + 255) & ~(size_t)255;
    return p;
  };
  // ---- persistent (~11.4 MB) ----
  int* dflag = (int*)alloc(256);
  bf16* Wcat = (bf16*)alloc((size_t)2 * NP * KC * 2);
  float* bcat = (float*)alloc((size_t)2 * NP * 4);
  bf16* lnp = (bf16*)alloc((size_t)C_ * KC * 2);
  bf16* ggct = (bf16*)alloc((size_t)2 * C_ * C_ * 2);
  bf16* Sp = (bf16*)alloc((size_t)B_ * KC * 2);
  const size_t phase_base = off;
  // ---- phase 1 (LSTM): ~94 MB -> peak ~106 MB ----
  float* Spf = (float*)alloc((size_t)B_ * KC * 4);
  bf16* hpad = (bf16*)alloc((size_t)4 * B_ * HP * 2);
  float* cst = (float*)alloc((size_t)2 * B_ * HP * 4);
  bf16* Hb = (bf16*)alloc((size_t)T_ * B_ * H_ * 2);
  // ---- phase 2 (graph): ~80 MB, aliases phase 1 ----
  off = phase_base;
  float* hbuf = (float*)alloc((size_t)B_ * C_ * 4);
  bf16* hb16 = (bf16*)alloc((size_t)B_ * C_ * 2);
  bf16* m1t = (bf16*)alloc((size_t)C_ * B_ * 2);     // m transposed [c][s]
  bf16* aggb = (bf16*)alloc((size_t)B_ * C_ * 2);
  bf16* Acnt = (bf16*)alloc((size_t)B_ * B_ * 2);    // dense adjacency counts
  float* gi = (float*)alloc((size_t)B_ * 3072 * 4);  // cnt(i32, 16MB) aliases head of gi
  float* gh = (float*)alloc((size_t)B_ * 3072 * 4);
  int* cnt = (int*)gi;

  // ---- dtype detection + prep ----
  detect_dtype<<<1, 256, 0, stream>>>((const unsigned short*)emb, dflag);
  prep_wcat<<<(2 * NP * KC) / 256, 256, 0, stream>>>(Wih_f, Whh_f, bih_f, bhh_f,
                                                     Wih_b, Whh_b, bih_b, bhh_b, Wcat, bcat, dflag);
  labelnorm<<<C_, 256, 0, stream>>>(label, lnp, dflag);
  transpose_ggc<<<(2 * C_ * C_) / 256, 256, 0, stream>>>(ggcw, ggct, dflag);
  zero_u4<<<(4 * B_ * HP * 2 / 16 + 255) / 256, 256, 0, stream>>>((uint4*)hpad, 4 * B_ * HP * 2 / 16);
  zero_u4<<<(2 * B_ * HP * 4 / 16 + 255) / 256, 256, 0, stream>>>((uint4*)cst, 2 * B_ * HP * 4 / 16);
  zero_u4<<<(B_ * KC * 4 / 16 + 255) / 256, 256, 0, stream>>>((uint4*)Spf, B_ * KC * 4 / 16);

  // ---- phase 1a: backward LSTM (stores Hb); 320 blocks ----
  for (int s = 0; s < T_; ++s)
    lstm_step<<<dim3(NP / 128, B_ / 64, 1), 256, 0, stream>>>(emb, x, Wcat, bcat, hpad, cst,
                                                              Hb, Spf, 1, s, dflag);
  // ---- phase 1b: forward LSTM; z=1 plane folds step s-1 into Spf ----
  for (int s = 0; s < T_; ++s)
    lstm_step<<<dim3(NP / 128, B_ / 64, 2), 256, 0, stream>>>(emb, x, Wcat, bcat, hpad, cst,
                                                              Hb, Spf, 0, s, dflag);
  normacc<<<B_ / 4, 256, 0, stream>>>(hpad /*fwd h63: dir0 parity0*/, Hb, Spf, T_ - 1);
  spcvt<<<(B_ * KC) / 256, 256, 0, stream>>>(Spf, Sp);

  // ---- phase 2: label scores + GatedGraphConv (dense-adjacency GEMM) + proj ----
  gemm_bt<<<dim3(C_ / 128, B_ / 128), 256, 0, stream>>>(Sp, KC, lnp, KC, nullptr,
                                                        hbuf, hb16, C_, KC, nullptr, 0);
  // adjacency counts (built once, reused by both layers)
  zero_u4<<<(B_ * B_ * 4 / 16 + 255) / 256, 256, 0, stream>>>((uint4*)cnt, B_ * B_ * 4 / 16);
  edge_cnt<<<NE_ / 256, 256, 0, stream>>>(ei, cnt);
  cnt2bf<<<(B_ * B_) / 256, 256, 0, stream>>>(cnt, Acnt);
  for (int l = 0; l < 2; ++l) {
    // m1t[c][s] = sum_k ggcw[l][k][c] * h[s][k]   (A/W roles swapped)
    gemm_bt<<<dim3(B_ / 128, C_ / 128), 256, 0, stream>>>(ggct + (size_t)l * C_ * C_, C_,
                                                          hb16, C_, nullptr,
                                                          nullptr, m1t, B_, C_, nullptr, 0);
    // agg[d][c] = sum_s Acnt[d][s] * m1t[c][s]  (replaces 875us atomic scatter)
    gemm_bt<<<dim3(C_ / 128, B_ / 128), 256, 0, stream>>>(Acnt, B_, m1t, B_, nullptr,
                                                          nullptr, aggb, C_, B_, nullptr, 0);
    gemm_bt<<<dim3(3072 / 128, B_ / 128), 256, 0, stream>>>(aggb, C_, gWih, C_, gbih,
                                                            gi, nullptr, 3072, C_, dflag, 0);
    gemm_bt<<<dim3(3072 / 128, B_ / 128), 256, 0, stream>>>(hb16, C_, gWhh, C_, gbhh,
                                                            gh, nullptr, 3072, C_, dflag, 0);
    gru_ew<<<(B_ * C_) / 256, 256, 0, stream>>>(gi, gh, hbuf, hb16);
  }
  gemm_bt<<<dim3(C_ / 128, B_ / 128), 256, 0, stream>>>(hb16, C_, projW, C_, projb,
                                                        (float*)d_out, (bf16*)d_out, C_, C_,
                                                        dflag, 1);
}